// Round 1
// baseline (907.294 us; speedup 1.0000x reference)
//
#include <hip/hip_runtime.h>

#define GH 14
#define GW 14

__global__ __launch_bounds__(256) void roi_align_kernel(
    const float* __restrict__ fmap,
    const float* __restrict__ rois,
    const int*   __restrict__ imgh,
    float*       __restrict__ out,
    int C, int H, int W)
{
    const int per_box = C * GH * GW;              // 256*196 = 50176
    const int m   = blockIdx.y;
    const int idx = blockIdx.x * blockDim.x + threadIdx.x;
    if (idx >= per_box) return;

    // idx = c*196 + i*14 + j  (output-linear within a box -> coalesced store)
    const int j = idx % GW;
    const int t = idx / GW;
    const int i = t % GH;
    const int c = t / GH;

    const float stride = (float)imgh[0] / (float)H;   // 800/200 = 4.0

    const float* r = rois + (size_t)m * 6;
    const int   b  = (int)r[0];            // batch idx stored as float
    const float x1 = r[2] / stride;
    const float y1 = r[3] / stride;
    const float x2 = r[4] / stride;
    const float y2 = r[5] / stride;

    const float ti = (float)i / (float)(GH - 1);
    const float tj = (float)j / (float)(GW - 1);
    const float ys = y1 + (y2 - y1) * ti;
    const float xs = x1 + (x2 - x1) * tj;

    const bool my = (ys >= 0.0f) && (ys <= (float)(H - 1));
    const bool mx = (xs >= 0.0f) && (xs <= (float)(W - 1));

    const float y0f = floorf(ys);
    const float x0f = floorf(xs);
    const float ly  = ys - y0f;
    const float lx  = xs - x0f;

    const int y0  = (int)fminf(fmaxf(y0f,        0.0f), (float)(H - 1));
    const int y1i = (int)fminf(fmaxf(y0f + 1.0f, 0.0f), (float)(H - 1));
    const int x0  = (int)fminf(fmaxf(x0f,        0.0f), (float)(W - 1));
    const int x1i = (int)fminf(fmaxf(x0f + 1.0f, 0.0f), (float)(W - 1));

    const float* p = fmap + ((size_t)b * C + c) * (size_t)(H * W);
    const float g00 = p[y0  * W + x0 ];
    const float g01 = p[y0  * W + x1i];
    const float g10 = p[y1i * W + x0 ];
    const float g11 = p[y1i * W + x1i];

    float v = g00 * (1.0f - ly) * (1.0f - lx)
            + g01 * (1.0f - ly) * lx
            + g10 * ly * (1.0f - lx)
            + g11 * ly * lx;
    v = (my && mx) ? v : 0.0f;

    out[(size_t)m * per_box + idx] = v;
}

extern "C" void kernel_launch(void* const* d_in, const int* in_sizes, int n_in,
                              void* d_out, int out_size, void* d_ws, size_t ws_size,
                              hipStream_t stream) {
    const float* fmap = (const float*)d_in[0];   // [N=4, C=256, H=200, W=200]
    const float* rois = (const float*)d_in[1];   // [M, 6] (n, score, x1, y1, x2, y2)
    const int*   imgh = (const int*)d_in[2];     // scalar 800

    float* out = (float*)d_out;

    const int C = 256, H = 200, W = 200;
    const int M = in_sizes[1] / 6;               // 2048
    const int per_box = C * GH * GW;             // 50176
    const int blocks_x = (per_box + 255) / 256;  // 196

    dim3 grid(blocks_x, M);
    roi_align_kernel<<<grid, 256, 0, stream>>>(fmap, rois, imgh, out, C, H, W);
}